// Round 1
// baseline (1939.444 us; speedup 1.0000x reference)
//
#include <hip/hip_runtime.h>
#include <hip/hip_fp16.h>

// LSTM: B=512, T=1024, I=64, H=128, C=10
// Persistent kernel: 32 workgroups x 512 threads; each WG owns 16 batch rows
// for the whole sequence. Weights resident in VGPRs as fp16 MFMA fragments.
// Per step: gates = [x_t, h] @ Wall^T via mfma_f32_16x16x32_f16 (fp32 accum),
// gate nonlinearities + c/h update fully in registers, h written back to LDS
// as fp16 (double-buffered), ONE barrier per step.

typedef _Float16 f16x8 __attribute__((ext_vector_type(8)));
typedef float    f32x4 __attribute__((ext_vector_type(4)));

constexpr int Bc   = 16;    // batch rows per workgroup (MFMA M)
constexpr int Tn   = 1024;
constexpr int In   = 64;
constexpr int Hn   = 128;
constexpr int Cn   = 10;
constexpr int Kn   = 192;   // I + H
constexpr int RS   = 200;   // padded row stride in fp16 elems (400 B -> 2-way bank alias, free)

__global__ __launch_bounds__(512, 2)
void lstm_persist(const float* __restrict__ x,
                  const float* __restrict__ Wf, const float* __restrict__ bf,
                  const float* __restrict__ Wo, const float* __restrict__ bo,
                  const float* __restrict__ Wi, const float* __restrict__ bi,
                  const float* __restrict__ Wg, const float* __restrict__ bg,
                  const float* __restrict__ Wfc, const float* __restrict__ bfc,
                  float* __restrict__ out)
{
    __shared__ __align__(16) _Float16 comb[2][Bc][RS];   // [x(64) | h(128) | pad(8)]
    __shared__ float h32[Bc][Hn];                        // final-step h, fp32

    const int tid  = threadIdx.x;
    const int lane = tid & 63;
    const int wv   = tid >> 6;        // wave 0..7 -> owns jh in [16*wv, 16*wv+16)
    const int l15  = lane & 15;
    const int lg   = lane >> 4;       // k-group 0..3
    const int b0   = blockIdx.x * Bc;
    const int jh0  = wv * 16;

    // ---- load weight fragments (fp16) into registers, once ----
    // B-frag for tile (gt, kt): lane l holds W[jh0 + (l&15) + 128*gt][kt*32 + lg*8 + e], e=0..7
    const float* Wptr[4] = {Wf, Wo, Wi, Wg};
    const float* bptr[4] = {bf, bo, bi, bg};
    f16x8 wfrag[4][6];
    float bias[4];
#pragma unroll
    for (int gt = 0; gt < 4; ++gt) {
        const float* W = Wptr[gt];
        const int jrow = jh0 + l15;
#pragma unroll
        for (int kt = 0; kt < 6; ++kt) {
            const int base = jrow * Kn + kt * 32 + lg * 8;
            const float4 w0 = *reinterpret_cast<const float4*>(&W[base]);
            const float4 w1 = *reinterpret_cast<const float4*>(&W[base + 4]);
            f16x8 h;
            h[0] = (_Float16)w0.x; h[1] = (_Float16)w0.y;
            h[2] = (_Float16)w0.z; h[3] = (_Float16)w0.w;
            h[4] = (_Float16)w1.x; h[5] = (_Float16)w1.y;
            h[6] = (_Float16)w1.z; h[7] = (_Float16)w1.w;
            wfrag[gt][kt] = h;
        }
        bias[gt] = bptr[gt][jh0 + l15];
    }

    // ---- init: c = 0, h(0) = 0 in comb[0], load x(t=0) ----
    float c[4] = {0.f, 0.f, 0.f, 0.f};
    float hreg[4] = {0.f, 0.f, 0.f, 0.f};

    {
        const int row = tid >> 5;          // 0..15
        const int q   = tid & 31;
        // zero h region (cols 64..191), 4 halfs per thread
#pragma unroll
        for (int e = 0; e < 4; ++e) comb[0][row][In + q * 4 + e] = (_Float16)0.f;
        // x(0): 2 floats per thread
        const float2 xv = *reinterpret_cast<const float2*>(
            &x[((size_t)(b0 + row) * Tn + 0) * In + q * 2]);
        comb[0][row][q * 2]     = (_Float16)xv.x;
        comb[0][row][q * 2 + 1] = (_Float16)xv.y;
    }
    __syncthreads();

    const int xrow = tid >> 5;
    const int xi   = (tid & 31) * 2;

    // ---- time loop ----
#pragma unroll 2
    for (int t = 0; t < Tn; ++t) {
        const int cur = t & 1;
        const int nxt = cur ^ 1;

        // prefetch x(t+1) early (global -> regs); dead (re-)load on last step
        const int tn = (t + 1 < Tn) ? (t + 1) : (Tn - 1);
        const float2 xv = *reinterpret_cast<const float2*>(
            &x[((size_t)(b0 + xrow) * Tn + tn) * In + xi]);

        // gates = bias + [x,h] @ W^T  (fp16 MFMA, fp32 accum)
        f32x4 acc[4];
#pragma unroll
        for (int gt = 0; gt < 4; ++gt) acc[gt] = (f32x4){bias[gt], bias[gt], bias[gt], bias[gt]};

#pragma unroll
        for (int kt = 0; kt < 6; ++kt) {
            const f16x8 a = *reinterpret_cast<const f16x8*>(&comb[cur][l15][kt * 32 + lg * 8]);
#pragma unroll
            for (int gt = 0; gt < 4; ++gt)
                acc[gt] = __builtin_amdgcn_mfma_f32_16x16x32_f16(a, wfrag[gt][kt], acc[gt], 0, 0, 0);
        }

        // nonlinearities + state update, all in registers.
        // lane mapping (m89): reg r, lane l -> row = lg*4 + r, jh = jh0 + l15
#pragma unroll
        for (int r = 0; r < 4; ++r) {
            const float fg = 1.f / (1.f + __expf(-acc[0][r]));
            const float og = 1.f / (1.f + __expf(-acc[1][r]));
            const float ig = 1.f / (1.f + __expf(-acc[2][r]));
            const float gg = 1.f - 2.f / (__expf(2.f * acc[3][r]) + 1.f);
            c[r] = c[r] * fg + ig * gg;
            hreg[r] = c[r] * og;
        }

        // write h(t+1) fp16 into next buffer
#pragma unroll
        for (int r = 0; r < 4; ++r)
            comb[nxt][lg * 4 + r][In + jh0 + l15] = (_Float16)hreg[r];

        // write x(t+1) fp16 into next buffer
        comb[nxt][xrow][xi]     = (_Float16)xv.x;
        comb[nxt][xrow][xi + 1] = (_Float16)xv.y;

        __syncthreads();
    }

    // ---- final FC: out = h @ Wfc^T + bfc, using fp32 h ----
#pragma unroll
    for (int r = 0; r < 4; ++r) h32[lg * 4 + r][jh0 + l15] = hreg[r];
    __syncthreads();

    if (tid < Bc * Cn) {
        const int row = tid / Cn;
        const int cc  = tid % Cn;
        float a = bfc[cc];
#pragma unroll 4
        for (int jh = 0; jh < Hn; ++jh)
            a += h32[row][jh] * Wfc[cc * Hn + jh];
        out[(size_t)(b0 + row) * Cn + cc] = a;
    }
}

extern "C" void kernel_launch(void* const* d_in, const int* in_sizes, int n_in,
                              void* d_out, int out_size, void* d_ws, size_t ws_size,
                              hipStream_t stream) {
    const float* xp  = (const float*)d_in[0];
    const float* Wfp = (const float*)d_in[1];
    const float* bfp = (const float*)d_in[2];
    const float* Wop = (const float*)d_in[3];
    const float* bop = (const float*)d_in[4];
    const float* Wip = (const float*)d_in[5];
    const float* bip = (const float*)d_in[6];
    const float* Wgp = (const float*)d_in[7];
    const float* bgp = (const float*)d_in[8];
    const float* Wfc = (const float*)d_in[9];
    const float* bfc = (const float*)d_in[10];
    float* outp = (float*)d_out;

    lstm_persist<<<512 / Bc, 512, 0, stream>>>(xp, Wfp, bfp, Wop, bop, Wip, bip,
                                               Wgp, bgp, Wfc, bfc, outp);
}

// Round 2
// 1634.272 us; speedup vs baseline: 1.1867x; 1.1867x over previous
//
#include <hip/hip_runtime.h>
#include <hip/hip_fp16.h>

// LSTM: B=512, T=1024, I=64, H=128, C=10
// Persistent kernel: 32 WGs x 256 threads (4 waves); each WG owns 16 batch rows
// for the whole sequence. Weights resident in VGPRs as fp16 MFMA B-fragments
// (each wave owns a 32-wide jh slice x 4 gates = 48 fragments).
// Per step: gates = [x_t, h] @ Wall^T via mfma_f32_16x16x32_f16 (fp32 accum),
// gate nonlinearities + c/h update in registers, h written back to LDS as fp16
// (double-buffered, XOR-swizzled rows), ONE barrier per step.
// x(t) is fed through a depth-2 register FIFO (float4/thread) so HBM latency
// stays off the per-step critical path.

typedef _Float16 f16x8 __attribute__((ext_vector_type(8)));
typedef _Float16 f16x4 __attribute__((ext_vector_type(4)));
typedef float    f32x4 __attribute__((ext_vector_type(4)));

constexpr int Bc   = 16;    // batch rows per workgroup (MFMA M)
constexpr int Tn   = 1024;
constexpr int In   = 64;
constexpr int Hn   = 128;
constexpr int Cn   = 10;
constexpr int Kn   = 192;   // I + H
constexpr int ROWB = Kn * 2;      // 384 bytes per row (16B-aligned, no pad; swizzle kills conflicts)
constexpr int BUFB = Bc * ROWB;   // 6144 bytes per buffer

// XOR swizzle: spreads the 8-row bank-alias of the transpose-pattern ds_read_b128.
// Bijective per row; preserves >=8B alignment (only flips byte bits 4..6).
__device__ __forceinline__ int swz(int row, int byteInRow) {
    return row * ROWB + (byteInRow ^ ((row & 7) << 4));
}

__global__ __launch_bounds__(256, 1)
void lstm_persist(const float* __restrict__ x,
                  const float* __restrict__ Wf, const float* __restrict__ bf,
                  const float* __restrict__ Wo, const float* __restrict__ bo,
                  const float* __restrict__ Wi, const float* __restrict__ bi,
                  const float* __restrict__ Wg, const float* __restrict__ bg,
                  const float* __restrict__ Wfc, const float* __restrict__ bfc,
                  float* __restrict__ out)
{
    __shared__ __align__(16) char comb[2 * BUFB];   // fp16 [row 0..15][x(64) | h(128)], swizzled
    __shared__ float h32[Bc][Hn];                   // final-step h, fp32

    const int tid  = threadIdx.x;
    const int lane = tid & 63;
    const int wv   = tid >> 6;        // wave 0..3 -> owns jh in [32*wv, 32*wv+32)
    const int l15  = lane & 15;
    const int lg   = lane >> 4;       // k-group 0..3
    const int b0   = blockIdx.x * Bc;

    // ---- load weight fragments (fp16) into registers, once ----
    // wfrag[gt][kt][jt]: lane l holds W[wv*32 + jt*16 + l15][kt*32 + lg*8 + e], e=0..7
    const float* Wptr[4] = {Wf, Wo, Wi, Wg};
    const float* bptr[4] = {bf, bo, bi, bg};
    f16x8 wfrag[4][6][2];
    float bias[4][2];
#pragma unroll
    for (int gt = 0; gt < 4; ++gt) {
        const float* W = Wptr[gt];
#pragma unroll
        for (int jt = 0; jt < 2; ++jt) {
            const int jrow = wv * 32 + jt * 16 + l15;
#pragma unroll
            for (int kt = 0; kt < 6; ++kt) {
                const int base = jrow * Kn + kt * 32 + lg * 8;
                const float4 w0 = *reinterpret_cast<const float4*>(&W[base]);
                const float4 w1 = *reinterpret_cast<const float4*>(&W[base + 4]);
                f16x8 h;
                h[0] = (_Float16)w0.x; h[1] = (_Float16)w0.y;
                h[2] = (_Float16)w0.z; h[3] = (_Float16)w0.w;
                h[4] = (_Float16)w1.x; h[5] = (_Float16)w1.y;
                h[6] = (_Float16)w1.z; h[7] = (_Float16)w1.w;
                wfrag[gt][kt][jt] = h;
            }
            bias[gt][jt] = bptr[gt][jrow];
        }
    }

    // ---- init: c = 0, h(0) = 0 in buffer 0, stage x(t=0) ----
    float c[2][4];
#pragma unroll
    for (int jt = 0; jt < 2; ++jt)
#pragma unroll
        for (int r = 0; r < 4; ++r) c[jt][r] = 0.f;
    float hreg[2][4];

    const int xrow = tid >> 4;          // 0..15
    const int xi0  = (tid & 15) * 4;    // 0,4,...,60
    {
        // zero h region: 8 halfs per thread
        const int hc0 = In + (tid & 15) * 8;
#pragma unroll
        for (int e = 0; e < 8; ++e)
            *reinterpret_cast<_Float16*>(&comb[swz(xrow, (hc0 + e) * 2)]) = (_Float16)0.f;
        // x(0): float4 per thread
        const float4 xv = *reinterpret_cast<const float4*>(
            &x[((size_t)(b0 + xrow) * Tn + 0) * In + xi0]);
        f16x4 p; p[0] = (_Float16)xv.x; p[1] = (_Float16)xv.y;
                 p[2] = (_Float16)xv.z; p[3] = (_Float16)xv.w;
        *reinterpret_cast<f16x4*>(&comb[swz(xrow, xi0 * 2)]) = p;
    }

    // x register FIFO: xv0 = x(t+1), xv1 = x(t+2)
    const float* xbase = &x[(size_t)(b0 + xrow) * Tn * In + xi0];
    float4 xv0 = *reinterpret_cast<const float4*>(&xbase[(size_t)1 * In]);
    float4 xv1 = *reinterpret_cast<const float4*>(&xbase[(size_t)2 * In]);

    __syncthreads();

    // ---- time loop ----
#pragma unroll 2
    for (int t = 0; t < Tn; ++t) {
        const int cur = (t & 1) * BUFB;
        const int nxt = BUFB - cur;

        // stage x(t+1) into next buffer; refill FIFO (t+3)
        {
            f16x4 p; p[0] = (_Float16)xv0.x; p[1] = (_Float16)xv0.y;
                     p[2] = (_Float16)xv0.z; p[3] = (_Float16)xv0.w;
            *reinterpret_cast<f16x4*>(&comb[nxt + swz(xrow, xi0 * 2)]) = p;
            xv0 = xv1;
            const int tf = (t + 3 < Tn) ? (t + 3) : (Tn - 1);
            xv1 = *reinterpret_cast<const float4*>(&xbase[(size_t)tf * In]);
        }

        // A fragments: row l15, k-slice kt*32 + lg*8 (swizzled, conflict-free)
        f16x8 a[6];
#pragma unroll
        for (int kt = 0; kt < 6; ++kt)
            a[kt] = *reinterpret_cast<const f16x8*>(
                &comb[cur + swz(l15, kt * 64 + lg * 16)]);

        // gates = bias + [x,h] @ W^T  (fp16 MFMA, fp32 accum)
        f32x4 acc[4][2];
#pragma unroll
        for (int gt = 0; gt < 4; ++gt)
#pragma unroll
            for (int jt = 0; jt < 2; ++jt) {
                const float b = bias[gt][jt];
                acc[gt][jt] = (f32x4){b, b, b, b};
            }

#pragma unroll
        for (int kt = 0; kt < 6; ++kt)
#pragma unroll
            for (int gt = 0; gt < 4; ++gt)
#pragma unroll
                for (int jt = 0; jt < 2; ++jt)
                    acc[gt][jt] = __builtin_amdgcn_mfma_f32_16x16x32_f16(
                        a[kt], wfrag[gt][kt][jt], acc[gt][jt], 0, 0, 0);

        // nonlinearities + state update, in registers.
        // D layout: reg r, lane l -> batch row = lg*4 + r, jh = wv*32 + jt*16 + l15
#pragma unroll
        for (int jt = 0; jt < 2; ++jt)
#pragma unroll
            for (int r = 0; r < 4; ++r) {
                const float fg = 1.f / (1.f + __expf(-acc[0][jt][r]));
                const float og = 1.f / (1.f + __expf(-acc[1][jt][r]));
                const float ig = 1.f / (1.f + __expf(-acc[2][jt][r]));
                const float gg = 1.f - 2.f / (__expf(2.f * acc[3][jt][r]) + 1.f);
                c[jt][r] = c[jt][r] * fg + ig * gg;
                hreg[jt][r] = c[jt][r] * og;
            }

        // write h(t+1) fp16 into next buffer
#pragma unroll
        for (int jt = 0; jt < 2; ++jt)
#pragma unroll
            for (int r = 0; r < 4; ++r)
                *reinterpret_cast<_Float16*>(
                    &comb[nxt + swz(lg * 4 + r, (In + wv * 32 + jt * 16 + l15) * 2)]) =
                    (_Float16)hreg[jt][r];

        __syncthreads();
    }

    // ---- final FC: out = h @ Wfc^T + bfc, using fp32 h ----
#pragma unroll
    for (int jt = 0; jt < 2; ++jt)
#pragma unroll
        for (int r = 0; r < 4; ++r)
            h32[lg * 4 + r][wv * 32 + jt * 16 + l15] = hreg[jt][r];
    __syncthreads();

    if (tid < Bc * Cn) {
        const int row = tid / Cn;
        const int cc  = tid % Cn;
        float a2 = bfc[cc];
#pragma unroll 4
        for (int jh = 0; jh < Hn; ++jh)
            a2 += h32[row][jh] * Wfc[cc * Hn + jh];
        out[(size_t)(b0 + row) * Cn + cc] = a2;
    }
}

extern "C" void kernel_launch(void* const* d_in, const int* in_sizes, int n_in,
                              void* d_out, int out_size, void* d_ws, size_t ws_size,
                              hipStream_t stream) {
    const float* xp  = (const float*)d_in[0];
    const float* Wfp = (const float*)d_in[1];
    const float* bfp = (const float*)d_in[2];
    const float* Wop = (const float*)d_in[3];
    const float* bop = (const float*)d_in[4];
    const float* Wip = (const float*)d_in[5];
    const float* bip = (const float*)d_in[6];
    const float* Wgp = (const float*)d_in[7];
    const float* bgp = (const float*)d_in[8];
    const float* Wfc = (const float*)d_in[9];
    const float* bfc = (const float*)d_in[10];
    float* outp = (float*)d_out;

    lstm_persist<<<512 / Bc, 256, 0, stream>>>(xp, Wfp, bfp, Wop, bop, Wip, bip,
                                               Wgp, bgp, Wfc, bfc, outp);
}

// Round 3
// 1601.911 us; speedup vs baseline: 1.2107x; 1.0202x over previous
//
#include <hip/hip_runtime.h>
#include <hip/hip_fp16.h>

// LSTM: B=512, T=1024, I=64, H=128, C=10
// Persistent kernel: 32 WGs x 512 threads (8 waves, 2/SIMD for latency hiding);
// each WG owns 16 batch rows for the whole sequence. Weights resident in
// VGPRs/AGPRs as fp16 MFMA B-fragments (each wave owns a jh-16 slice x 4 gates
// = 24 fragments). Per step: gates = [x_t, h] @ Wall^T via
// mfma_f32_16x16x32_f16 (fp32 accum), gate nonlinearities + c/h update in
// registers, h written back to LDS as fp16 (double-buffered, XOR-swizzled
// rows -> conflict-free ds_read_b128), ONE barrier per step. x(t) fed through
// a depth-2 register FIFO so HBM latency stays off the critical path.

typedef _Float16 f16x8 __attribute__((ext_vector_type(8)));
typedef float    f32x4 __attribute__((ext_vector_type(4)));

constexpr int Bc   = 16;    // batch rows per workgroup (MFMA M)
constexpr int Tn   = 1024;
constexpr int In   = 64;
constexpr int Hn   = 128;
constexpr int Cn   = 10;
constexpr int Kn   = 192;   // I + H
constexpr int ROWB = Kn * 2;      // 384 bytes per row (16B-aligned, no pad)
constexpr int BUFB = Bc * ROWB;   // 6144 bytes per buffer

// XOR swizzle: spreads the 8-row bank-alias (384 % 128 == 0) of the
// transpose-pattern ds_read_b128. Bijective per row; flips only byte bits 4..6.
__device__ __forceinline__ int swz(int row, int byteInRow) {
    return row * ROWB + (byteInRow ^ ((row & 7) << 4));
}

__global__ __launch_bounds__(512, 2)
void lstm_persist(const float* __restrict__ x,
                  const float* __restrict__ Wf, const float* __restrict__ bf,
                  const float* __restrict__ Wo, const float* __restrict__ bo,
                  const float* __restrict__ Wi, const float* __restrict__ bi,
                  const float* __restrict__ Wg, const float* __restrict__ bg,
                  const float* __restrict__ Wfc, const float* __restrict__ bfc,
                  float* __restrict__ out)
{
    __shared__ __align__(16) char comb[2 * BUFB];   // fp16 [row 0..15][x(64) | h(128)], swizzled
    __shared__ float h32[Bc][Hn];                   // final-step h, fp32

    const int tid  = threadIdx.x;
    const int lane = tid & 63;
    const int wv   = tid >> 6;        // wave 0..7 -> owns jh in [16*wv, 16*wv+16)
    const int l15  = lane & 15;
    const int lg   = lane >> 4;       // k-group 0..3
    const int b0   = blockIdx.x * Bc;
    const int jh0  = wv * 16;

    // ---- load weight fragments (fp16) into registers, once ----
    // wfrag[gt][kt]: lane l holds W[jh0 + l15][kt*32 + lg*8 + e], e=0..7
    const float* Wptr[4] = {Wf, Wo, Wi, Wg};
    const float* bptr[4] = {bf, bo, bi, bg};
    f16x8 wfrag[4][6];
    float bias[4];
#pragma unroll
    for (int gt = 0; gt < 4; ++gt) {
        const float* W = Wptr[gt];
        const int jrow = jh0 + l15;
#pragma unroll
        for (int kt = 0; kt < 6; ++kt) {
            const int base = jrow * Kn + kt * 32 + lg * 8;
            const float4 w0 = *reinterpret_cast<const float4*>(&W[base]);
            const float4 w1 = *reinterpret_cast<const float4*>(&W[base + 4]);
            f16x8 h;
            h[0] = (_Float16)w0.x; h[1] = (_Float16)w0.y;
            h[2] = (_Float16)w0.z; h[3] = (_Float16)w0.w;
            h[4] = (_Float16)w1.x; h[5] = (_Float16)w1.y;
            h[6] = (_Float16)w1.z; h[7] = (_Float16)w1.w;
            wfrag[gt][kt] = h;
        }
        bias[gt] = bptr[gt][jrow];
    }

    // ---- init: c = 0, h(0) = 0 in buffer 0, stage x(t=0) ----
    float c[4]    = {0.f, 0.f, 0.f, 0.f};
    float hreg[4] = {0.f, 0.f, 0.f, 0.f};

    const int xrow = tid >> 5;          // 0..15
    const int xi0  = (tid & 31) * 2;    // 0,2,...,62
    {
        // zero h region: 4 halfs per thread (512 threads cover 16x128)
        const int hc0 = In + (tid & 31) * 4;
#pragma unroll
        for (int e = 0; e < 4; ++e)
            *reinterpret_cast<_Float16*>(&comb[swz(xrow, (hc0 + e) * 2)]) = (_Float16)0.f;
        // x(0): float2 per thread
        const float2 xv = *reinterpret_cast<const float2*>(
            &x[((size_t)(b0 + xrow) * Tn + 0) * In + xi0]);
        comb[swz(xrow, xi0 * 2)]     = 0;  // placeholder to keep type simple (overwritten below)
        _Float16* p0 = reinterpret_cast<_Float16*>(&comb[swz(xrow, xi0 * 2)]);
        p0[0] = (_Float16)xv.x;
        p0[1] = (_Float16)xv.y;
    }

    // x register FIFO: xv0 = x(t+1), xv1 = x(t+2)
    const float* xbase = &x[(size_t)(b0 + xrow) * Tn * In + xi0];
    float2 xv0 = *reinterpret_cast<const float2*>(&xbase[(size_t)1 * In]);
    float2 xv1 = *reinterpret_cast<const float2*>(&xbase[(size_t)2 * In]);

    __syncthreads();

    // ---- time loop ----
#pragma unroll 2
    for (int t = 0; t < Tn; ++t) {
        const int cur = (t & 1) * BUFB;
        const int nxt = BUFB - cur;

        // stage x(t+1) into next buffer; refill FIFO (t+3)
        {
            _Float16* p0 = reinterpret_cast<_Float16*>(&comb[nxt + swz(xrow, xi0 * 2)]);
            p0[0] = (_Float16)xv0.x;
            p0[1] = (_Float16)xv0.y;
            xv0 = xv1;
            const int tf = (t + 3 < Tn) ? (t + 3) : (Tn - 1);
            xv1 = *reinterpret_cast<const float2*>(&xbase[(size_t)tf * In]);
        }

        // A fragments: row l15, k-slice kt*32 + lg*8 (swizzled, conflict-free)
        f16x8 a[6];
#pragma unroll
        for (int kt = 0; kt < 6; ++kt)
            a[kt] = *reinterpret_cast<const f16x8*>(
                &comb[cur + swz(l15, kt * 64 + lg * 16)]);

        // gates = bias + [x,h] @ W^T  (fp16 MFMA, fp32 accum)
        f32x4 acc[4];
#pragma unroll
        for (int gt = 0; gt < 4; ++gt) {
            const float b = bias[gt];
            acc[gt] = (f32x4){b, b, b, b};
        }

#pragma unroll
        for (int kt = 0; kt < 6; ++kt)
#pragma unroll
            for (int gt = 0; gt < 4; ++gt)
                acc[gt] = __builtin_amdgcn_mfma_f32_16x16x32_f16(
                    a[kt], wfrag[gt][kt], acc[gt], 0, 0, 0);

        // nonlinearities + state update, in registers.
        // D layout: reg r, lane l -> batch row = lg*4 + r, jh = jh0 + l15
#pragma unroll
        for (int r = 0; r < 4; ++r) {
            const float fg = 1.f / (1.f + __expf(-acc[0][r]));
            const float og = 1.f / (1.f + __expf(-acc[1][r]));
            const float ig = 1.f / (1.f + __expf(-acc[2][r]));
            const float gg = 1.f - 2.f / (__expf(2.f * acc[3][r]) + 1.f);
            c[r] = c[r] * fg + ig * gg;
            hreg[r] = c[r] * og;
        }

        // write h(t+1) fp16 into next buffer
#pragma unroll
        for (int r = 0; r < 4; ++r)
            *reinterpret_cast<_Float16*>(
                &comb[nxt + swz(lg * 4 + r, (In + jh0 + l15) * 2)]) =
                (_Float16)hreg[r];

        __syncthreads();
    }

    // ---- final FC: out = h @ Wfc^T + bfc, using fp32 h ----
#pragma unroll
    for (int r = 0; r < 4; ++r)
        h32[lg * 4 + r][jh0 + l15] = hreg[r];
    __syncthreads();

    if (tid < Bc * Cn) {
        const int row = tid / Cn;
        const int cc  = tid % Cn;
        float a2 = bfc[cc];
#pragma unroll 4
        for (int jh = 0; jh < Hn; ++jh)
            a2 += h32[row][jh] * Wfc[cc * Hn + jh];
        out[(size_t)(b0 + row) * Cn + cc] = a2;
    }
}

extern "C" void kernel_launch(void* const* d_in, const int* in_sizes, int n_in,
                              void* d_out, int out_size, void* d_ws, size_t ws_size,
                              hipStream_t stream) {
    const float* xp  = (const float*)d_in[0];
    const float* Wfp = (const float*)d_in[1];
    const float* bfp = (const float*)d_in[2];
    const float* Wop = (const float*)d_in[3];
    const float* bop = (const float*)d_in[4];
    const float* Wip = (const float*)d_in[5];
    const float* bip = (const float*)d_in[6];
    const float* Wgp = (const float*)d_in[7];
    const float* bgp = (const float*)d_in[8];
    const float* Wfc = (const float*)d_in[9];
    const float* bfc = (const float*)d_in[10];
    float* outp = (float*)d_out;

    lstm_persist<<<512 / Bc, 512, 0, stream>>>(xp, Wfp, bfp, Wop, bop, Wip, bip,
                                               Wgp, bgp, Wfc, bfc, outp);
}

// Round 5
// 942.334 us; speedup vs baseline: 2.0581x; 1.6999x over previous
//
#include <hip/hip_runtime.h>
#include <hip/hip_fp16.h>

// LSTM: B=512, T=1024, I=64, H=128, C=10
// Persistent kernel: 32 WGs x 512 threads (8 waves, 2/SIMD); each WG owns 16
// batch rows for the whole sequence. Weights resident in VGPRs as fp16 MFMA
// B-fragments (24/wave). Per step: gates = [x_t, h] @ Wall^T via
// mfma_f32_16x16x32_f16 (fp32 accum); gate nonlinearities with RAW v_rcp_f32
// (no IEEE divide sequences!) + c/h update in registers; h written back to LDS
// fp16 (double-buffered, XOR-swizzled -> conflict-free ds_read_b128);
// ONE barrier per step. All LDS addresses hoisted out of the loop; loop body
// unrolled x2 so buffer parity is compile-time. x(t) via depth-2 reg FIFO.

typedef _Float16 f16x8 __attribute__((ext_vector_type(8)));
typedef __fp16   hf2   __attribute__((ext_vector_type(2)));   // cvt_pkrtz native type
typedef float    f32x4 __attribute__((ext_vector_type(4)));

constexpr int Bc   = 16;    // batch rows per workgroup (MFMA M)
constexpr int Tn   = 1024;
constexpr int In   = 64;
constexpr int Hn   = 128;
constexpr int Cn   = 10;
constexpr int Kn   = 192;   // I + H
constexpr int ROWB = Kn * 2;      // 384 bytes per row
constexpr int BUFB = Bc * ROWB;   // 6144 bytes per buffer

// XOR swizzle: spreads the 8-row bank alias (384 % 128 == 0) of the
// transpose-pattern ds_read_b128. Bijective per row; flips byte bits 4..6,
// preserving 16B alignment granularity within 16B slots.
__device__ __forceinline__ int swz(int row, int byteInRow) {
    return row * ROWB + (byteInRow ^ ((row & 7) << 4));
}

__global__ __launch_bounds__(512, 2)
void lstm_persist(const float* __restrict__ x,
                  const float* __restrict__ Wf, const float* __restrict__ bf,
                  const float* __restrict__ Wo, const float* __restrict__ bo,
                  const float* __restrict__ Wi, const float* __restrict__ bi,
                  const float* __restrict__ Wg, const float* __restrict__ bg,
                  const float* __restrict__ Wfc, const float* __restrict__ bfc,
                  float* __restrict__ out)
{
    __shared__ __align__(16) char comb[2 * BUFB];   // fp16 [row][x(64)|h(128)], swizzled
    __shared__ float h32[Bc][Hn];                   // final-step h, fp32

    const int tid  = threadIdx.x;
    const int lane = tid & 63;
    const int wv   = tid >> 6;        // wave 0..7 -> owns jh in [16*wv, 16*wv+16)
    const int l15  = lane & 15;
    const int lg   = lane >> 4;       // k-group 0..3
    const int b0   = blockIdx.x * Bc;
    const int jh0  = wv * 16;

    // ---- weight fragments (fp16) into registers, once ----
    // wfrag[gt][kt]: lane l holds W[jh0 + l15][kt*32 + lg*8 + e], e=0..7
    const float* Wptr[4] = {Wf, Wo, Wi, Wg};
    const float* bptr[4] = {bf, bo, bi, bg};
    f16x8 wfrag[4][6];
    float bias[4];
#pragma unroll
    for (int gt = 0; gt < 4; ++gt) {
        const float* W = Wptr[gt];
        const int jrow = jh0 + l15;
#pragma unroll
        for (int kt = 0; kt < 6; ++kt) {
            const int base = jrow * Kn + kt * 32 + lg * 8;
            const float4 w0 = *reinterpret_cast<const float4*>(&W[base]);
            const float4 w1 = *reinterpret_cast<const float4*>(&W[base + 4]);
            f16x8 h;
            h[0] = (_Float16)w0.x; h[1] = (_Float16)w0.y;
            h[2] = (_Float16)w0.z; h[3] = (_Float16)w0.w;
            h[4] = (_Float16)w1.x; h[5] = (_Float16)w1.y;
            h[6] = (_Float16)w1.z; h[7] = (_Float16)w1.w;
            wfrag[gt][kt] = h;
        }
        bias[gt] = bptr[gt][jrow];
    }

    // ---- hoisted LDS byte offsets (compile-time indexed only) ----
    const int xrow = tid >> 5;          // 0..15
    const int xi0  = (tid & 31) * 2;    // x col pair base
    int addrA[2][6], addrH[2][4], addrX[2];
#pragma unroll
    for (int kt = 0; kt < 6; ++kt) {
        const int o = swz(l15, (kt * 32 + lg * 8) * 2);
        addrA[0][kt] = o; addrA[1][kt] = BUFB + o;
    }
#pragma unroll
    for (int r = 0; r < 4; ++r) {
        const int o = swz(lg * 4 + r, (In + jh0 + l15) * 2);
        addrH[0][r] = o; addrH[1][r] = BUFB + o;
    }
    {
        const int o = swz(xrow, xi0 * 2);
        addrX[0] = o; addrX[1] = BUFB + o;
    }

    // ---- init: zero buffer 0, stage x(0), c = 0 ----
    float c[4]    = {0.f, 0.f, 0.f, 0.f};
    float hreg[4] = {0.f, 0.f, 0.f, 0.f};
    {
        // zero entire buffer 0 (x region overwritten by x(0) stage after barrier)
        for (int o = tid * 8; o < BUFB; o += 512 * 8)
            *reinterpret_cast<unsigned long long*>(comb + o) = 0ull;
    }
    __syncthreads();
    {
        const float2 xv = *reinterpret_cast<const float2*>(
            &x[((size_t)(b0 + xrow) * Tn + 0) * In + xi0]);
        *reinterpret_cast<hf2*>(comb + addrX[0]) =
            __builtin_amdgcn_cvt_pkrtz(xv.x, xv.y);
    }

    // x register FIFO: xv0 = x(t+1), xv1 = x(t+2)
    const float* xbase = &x[(size_t)(b0 + xrow) * Tn * In + xi0];
    float2 xv0 = *reinterpret_cast<const float2*>(&xbase[(size_t)1 * In]);
    float2 xv1 = *reinterpret_cast<const float2*>(&xbase[(size_t)2 * In]);

    __syncthreads();

    // ---- time loop: explicit 2-step unroll, P = buffer parity (literal) ----
#define LSTM_STEP(P, T)                                                        \
    {                                                                          \
        /* stage x(T+1) into buffer P^1; refill FIFO with x(T+3) */            \
        *reinterpret_cast<hf2*>(comb + addrX[(P) ^ 1]) =                       \
            __builtin_amdgcn_cvt_pkrtz(xv0.x, xv0.y);                          \
        xv0 = xv1;                                                             \
        {                                                                      \
            const int tf = ((T) + 3 < Tn) ? (T) + 3 : (Tn - 1);                \
            xv1 = *reinterpret_cast<const float2*>(&xbase[(size_t)tf * In]);   \
        }                                                                      \
        f16x8 a[6];                                                            \
        _Pragma("unroll")                                                      \
        for (int kt = 0; kt < 6; ++kt)                                         \
            a[kt] = *reinterpret_cast<const f16x8*>(comb + addrA[P][kt]);      \
        f32x4 acc[4];                                                          \
        _Pragma("unroll")                                                      \
        for (int gt = 0; gt < 4; ++gt) {                                       \
            const float bb = bias[gt];                                         \
            acc[gt] = (f32x4){bb, bb, bb, bb};                                 \
        }                                                                      \
        _Pragma("unroll")                                                      \
        for (int kt = 0; kt < 6; ++kt)                                         \
            _Pragma("unroll")                                                  \
            for (int gt = 0; gt < 4; ++gt)                                     \
                acc[gt] = __builtin_amdgcn_mfma_f32_16x16x32_f16(              \
                    a[kt], wfrag[gt][kt], acc[gt], 0, 0, 0);                   \
        /* gates: raw v_rcp, no IEEE divide. D layout: reg r, lane l ->        \
           batch row = lg*4+r, jh = jh0 + l15 */                               \
        _Pragma("unroll")                                                      \
        for (int r = 0; r < 4; ++r) {                                          \
            const float fg = __builtin_amdgcn_rcpf(1.f + __expf(-acc[0][r]));  \
            const float og = __builtin_amdgcn_rcpf(1.f + __expf(-acc[1][r]));  \
            const float ig = __builtin_amdgcn_rcpf(1.f + __expf(-acc[2][r]));  \
            const float gg = fmaf(                                             \
                -2.f, __builtin_amdgcn_rcpf(1.f + __expf(2.f * acc[3][r])),    \
                1.f);                                                          \
            c[r]    = fmaf(c[r], fg, ig * gg);                                 \
            hreg[r] = c[r] * og;                                               \
            *reinterpret_cast<_Float16*>(comb + addrH[(P) ^ 1][r]) =           \
                (_Float16)hreg[r];                                             \
        }                                                                      \
        __syncthreads();                                                       \
    }

    for (int t = 0; t < Tn; t += 2) {
        LSTM_STEP(0, t)
        LSTM_STEP(1, t + 1)
    }
#undef LSTM_STEP

    // ---- final FC: out = h @ Wfc^T + bfc, using fp32 h ----
#pragma unroll
    for (int r = 0; r < 4; ++r)
        h32[lg * 4 + r][jh0 + l15] = hreg[r];
    __syncthreads();

    if (tid < Bc * Cn) {
        const int row = tid / Cn;
        const int cc  = tid % Cn;
        float a2 = bfc[cc];
#pragma unroll 4
        for (int jh = 0; jh < Hn; ++jh)
            a2 += h32[row][jh] * Wfc[cc * Hn + jh];
        out[(size_t)(b0 + row) * Cn + cc] = a2;
    }
}

extern "C" void kernel_launch(void* const* d_in, const int* in_sizes, int n_in,
                              void* d_out, int out_size, void* d_ws, size_t ws_size,
                              hipStream_t stream) {
    const float* xp  = (const float*)d_in[0];
    const float* Wfp = (const float*)d_in[1];
    const float* bfp = (const float*)d_in[2];
    const float* Wop = (const float*)d_in[3];
    const float* bop = (const float*)d_in[4];
    const float* Wip = (const float*)d_in[5];
    const float* bip = (const float*)d_in[6];
    const float* Wgp = (const float*)d_in[7];
    const float* bgp = (const float*)d_in[8];
    const float* Wfc = (const float*)d_in[9];
    const float* bfc = (const float*)d_in[10];
    float* outp = (float*)d_out;

    lstm_persist<<<512 / Bc, 512, 0, stream>>>(xp, Wfp, bfp, Wop, bop, Wip, bip,
                                               Wgp, bgp, Wfc, bfc, outp);
}